// Round 2
// baseline (54.670 us; speedup 1.0000x reference)
//
#include <hip/hip_runtime.h>
#include <hip/hip_cooperative_groups.h>

namespace cg = cooperative_groups;

// GraphAttentionLayer collapses algebraically:
//   a[i,j] = s[i]  (constant over j)  =>  softmax row = uniform 1/N
//   out[i] = mean_j h[j] = (mean_j x[j]) @ W.T + b    (same for every row i)
// Single cooperative kernel: partial colsums -> grid.sync() ->
// (redundant per block) reduce + matvec -> broadcast slice of output.

#define N_ROWS 8192
#define F_IN   256
#define F_OUT  128
#define NBLK   256
#define RPB    (N_ROWS / NBLK)   // 32 rows per block

__global__ void __launch_bounds__(256, 1)
gat_fused(const float* __restrict__ x, const float* __restrict__ W,
          const float* __restrict__ b, float* __restrict__ part,
          float* __restrict__ out)
{
    const int t   = threadIdx.x;   // 0..255
    const int blk = blockIdx.x;    // 0..255

    // ---- Phase 1: partial column sums of x over this block's 32 rows ----
    {
        const float* xp = x + (size_t)blk * RPB * F_IN + t;
        float s = 0.f;
#pragma unroll
        for (int r = 0; r < RPB; ++r)
            s += xp[r * F_IN];
        part[blk * F_IN + t] = s;   // [NBLK][F_IN] float
    }

    cg::this_grid().sync();

    // ---- Phase 2 (redundant in every block; deterministic fixed order) ----
    __shared__ double xbar[F_IN];
    __shared__ float  mrow[F_OUT];
    {
        // 4-way split accumulators to break the dependent-add chain
        double a0 = 0.0, a1 = 0.0, a2 = 0.0, a3 = 0.0;
#pragma unroll 8
        for (int p = 0; p < NBLK; p += 4) {
            a0 += (double)part[(p + 0) * F_IN + t];
            a1 += (double)part[(p + 1) * F_IN + t];
            a2 += (double)part[(p + 2) * F_IN + t];
            a3 += (double)part[(p + 3) * F_IN + t];
        }
        xbar[t] = ((a0 + a1) + (a2 + a3)) * (1.0 / (double)N_ROWS);
    }
    __syncthreads();
    if (t < F_OUT) {
        const float* wr = W + (size_t)t * F_IN;
        double a0 = 0.0, a1 = 0.0, a2 = 0.0, a3 = 0.0;
#pragma unroll 8
        for (int k = 0; k < F_IN; k += 4) {
            a0 += xbar[k + 0] * (double)wr[k + 0];
            a1 += xbar[k + 1] * (double)wr[k + 1];
            a2 += xbar[k + 2] * (double)wr[k + 2];
            a3 += xbar[k + 3] * (double)wr[k + 3];
        }
        mrow[t] = (float)(((a0 + a1) + (a2 + a3)) + (double)b[t]);
    }
    __syncthreads();

    // ---- Phase 3: broadcast mrow into this block's 32 output rows ----
    // 32 rows * 128 f32 = 1024 float4; 256 threads -> 4 stores each.
    const float4 v = ((const float4*)mrow)[t & (F_OUT / 4 - 1)];  // (t+j*256)&31 == t&31
    float4* out4 = (float4*)out + (size_t)blk * (RPB * F_OUT / 4);
#pragma unroll
    for (int j = 0; j < 4; ++j)
        out4[t + j * 256] = v;
}

extern "C" void kernel_launch(void* const* d_in, const int* in_sizes, int n_in,
                              void* d_out, int out_size, void* d_ws, size_t ws_size,
                              hipStream_t stream) {
    const float* x = (const float*)d_in[0];   // [8192, 256]
    // d_in[1] = adj (unused)
    const float* W = (const float*)d_in[2];   // [128, 256]
    const float* b = (const float*)d_in[3];   // [128]
    // d_in[4] = Wa, d_in[5] = ba (algebraically dead)
    float* out  = (float*)d_out;              // [8192, 128]
    float* part = (float*)d_ws;               // NBLK*F_IN floats = 256 KB

    void* args[] = {(void*)&x, (void*)&W, (void*)&b, (void*)&part, (void*)&out};
    hipLaunchCooperativeKernel((const void*)gat_fused, dim3(NBLK), dim3(256),
                               args, 0, stream);
}

// Round 3
// 20.352 us; speedup vs baseline: 2.6862x; 2.6862x over previous
//
#include <hip/hip_runtime.h>

// GraphAttentionLayer collapses algebraically:
//   a[i,j] = s[i] (constant over j) => softmax row = uniform 1/N
//   out[i] = mean_j h[j] = (mean_j x[j]) @ W.T + b   (identical for every row i)
// Two plain kernels (cooperative launch measured 2.3x WORSE in graph replay):
//   K1: partial column sums of x
//   K2: redundant-per-block reduce + matvec (deterministic), write own slice.

#define N_ROWS 8192
#define F_IN   256
#define F_OUT  128
#define NB1    256
#define RPB1   (N_ROWS / NB1)   // 32 rows per K1 block
#define NB2    128
#define RPB2   (N_ROWS / NB2)   // 64 rows per K2 block

__global__ void __launch_bounds__(256)
gat_colsum(const float* __restrict__ x, float* __restrict__ part) {
    const int t = threadIdx.x, blk = blockIdx.x;
    const float* xp = x + (size_t)blk * RPB1 * F_IN + t;
    float s = 0.f;
#pragma unroll
    for (int r = 0; r < RPB1; ++r)
        s += xp[r * F_IN];
    part[blk * F_IN + t] = s;          // [NB1][F_IN] float
}

__global__ void __launch_bounds__(256, 1)
gat_finish(const float* __restrict__ part, const float* __restrict__ W,
           const float* __restrict__ b, float* __restrict__ out) {
    __shared__ float  Wl[F_OUT][F_IN + 1];   // +1 pad: conflict-free Wl[t][k] reads
    __shared__ double xbar[F_IN];
    __shared__ float  mrow[F_OUT];
    const int t = threadIdx.x;

    // Stage W into LDS, coalesced float4 global reads.
    const float4* W4 = (const float4*)W;     // 8192 float4
#pragma unroll
    for (int j = 0; j < (F_OUT * F_IN / 4) / 256; ++j) {   // 32 iters
        float4 v = W4[j * 256 + t];
        int idx = (j * 256 + t) * 4;
        int f = idx >> 8;                    // row (f_in stride 256)
        int k = idx & 255;
        Wl[f][k] = v.x; Wl[f][k + 1] = v.y; Wl[f][k + 2] = v.z; Wl[f][k + 3] = v.w;
    }

    // Reduce partials: thread t sums column t over all 256 partial blocks.
    // Fixed order + double => bitwise-identical in every block (deterministic).
    double a0 = 0.0, a1 = 0.0, a2 = 0.0, a3 = 0.0;
#pragma unroll 8
    for (int p = 0; p < NB1; p += 4) {
        a0 += (double)part[(p + 0) * F_IN + t];
        a1 += (double)part[(p + 1) * F_IN + t];
        a2 += (double)part[(p + 2) * F_IN + t];
        a3 += (double)part[(p + 3) * F_IN + t];
    }
    xbar[t] = ((a0 + a1) + (a2 + a3)) * (1.0 / (double)N_ROWS);
    __syncthreads();

    if (t < F_OUT) {
        double c0 = 0.0, c1 = 0.0, c2 = 0.0, c3 = 0.0;
#pragma unroll 8
        for (int k = 0; k < F_IN; k += 4) {
            c0 += xbar[k + 0] * (double)Wl[t][k + 0];
            c1 += xbar[k + 1] * (double)Wl[t][k + 1];
            c2 += xbar[k + 2] * (double)Wl[t][k + 2];
            c3 += xbar[k + 3] * (double)Wl[t][k + 3];
        }
        mrow[t] = (float)(((c0 + c1) + (c2 + c3)) + (double)b[t]);
    }
    __syncthreads();

    // Write this block's 64 output rows: 64*128 floats = 2048 float4, 8/thread.
    const float4 v = ((const float4*)mrow)[t & (F_OUT / 4 - 1)]; // (t+j*256)&31 == t&31
    float4* o4 = (float4*)out + (size_t)blockIdx.x * (RPB2 * F_OUT / 4);
#pragma unroll
    for (int j = 0; j < 8; ++j)
        o4[t + j * 256] = v;
}

extern "C" void kernel_launch(void* const* d_in, const int* in_sizes, int n_in,
                              void* d_out, int out_size, void* d_ws, size_t ws_size,
                              hipStream_t stream) {
    const float* x = (const float*)d_in[0];   // [8192, 256]
    // d_in[1] = adj (unused)
    const float* W = (const float*)d_in[2];   // [128, 256]
    const float* b = (const float*)d_in[3];   // [128]
    // d_in[4] = Wa, d_in[5] = ba (algebraically dead)
    float* out  = (float*)d_out;              // [8192, 128]
    float* part = (float*)d_ws;               // NB1*F_IN floats = 256 KB

    gat_colsum<<<NB1, 256, 0, stream>>>(x, part);
    gat_finish<<<NB2, 256, 0, stream>>>(part, W, b, out);
}